// Round 1
// baseline (37922.546 us; speedup 1.0000x reference)
//
#include <hip/hip_runtime.h>
#include <cmath>

// ESN forward scan on MI355X — round 4.
//
// Round-3 rocprof: dur 16.23 ms (3.96 us/step), VALUBusy 12.4%, FETCH 825 MB,
// HBM 0.8%, MfmaUtil 0. VALU work is only ~0.5 us/step -> ~3.5 us/step is
// exchange latency vs a ~1.4 us structural floor (one L3 hop + compute).
//
// Theory: tagged-payload polling is SELF-CONGESTING. Each poll round re-reads
// the whole 16 KB exchange buffer per block (4 MB/round chip-wide, ~8-10
// rounds/step from the VALUBusy arithmetic) with cache-bypass loads over the
// same 128 hot lines -> >10 TB/s of fabric traffic that queues behind itself
// and slows the very publishes it is waiting for.
//
// Round-4 redesign — separate completion flags from payload:
//   1. Per-WAVE byte flags (1024 = 256 blocks x 4 waves), ping-pong by step
//      parity, value = step tag mod 256 (slot values advance by 2; max skew
//      between blocks is ~2 steps, so the byte compare is unambiguous).
//      Publisher protocol: payload global_store_short sc0 sc1 (write-through
//      to the coherence point) -> s_waitcnt vmcnt(0) (release fence) ->
//      flag byte store. This is exactly how agent-scope release is lowered.
//   2. Only wave 0 of each block polls: 64 lanes x dwordx4 covers the whole
//      1 KB flag array = 8 hot lines/round (64x less poll footprint than
//      round 3), then __syncthreads releases the sibling waves. Reader-side
//      ordering (flag load -> payload load) comes from the branch + barrier:
//      in-order waves cannot issue the payload loads before the poll exits.
//   3. Payload (8 KB packed fp16, NO tags) is read EXACTLY ONCE per step:
//      each thread 2x global_load_dwordx4 sc0 sc1 (split halves so the
//      ds_write_b128 staging stays conflict-free at stride 16 B) -> LDS ->
//      barrier -> same per-lane h8 fragment reads as round 3. The per-word
//      tag-unpack VALU disappears (publishers emit the packed layout).
//   4. Critical-path trims: x[] staged once in LDS (48 KB); tanh via
//      v_exp_f32 + rcp identity (error ~1e-6, far below the 3.9e-3 fp16
//      exchange quantization); out[] store moved AFTER the flag store.
//
// Overwrite safety (ping-pong distance 2): a wave publishes into pay[p] at
// step t+1 only after its flag-wait saw ALL 1024 flags at tag t+1, which
// happens-after every wave finished its step-t payload reads of pay[p].
//
// Predicted: step 3.96 -> ~1.6-2.2 us (dur 16.3 -> 6.5-9 ms), FETCH_SIZE
// drops toward the one-time 64 MB weight read, VALUBusy ~2x.

#define T_STEPS  4096
#define R_SIZE   4096
#define I_SIZE   3
#define OUT_COLS (R_SIZE + I_SIZE)   // 4099
#define NB       256                 // blocks == CUs; all co-resident
#define BT       256                 // threads per block (4 waves)
#define RPB      16                  // rows per block
#define RPW      4                   // rows per wave
#define NWAVES   4
#define NFLAGS   (NB * NWAVES)       // 1024 per-wave flags
#define LEAK     0.1f

typedef _Float16 h2 __attribute__((ext_vector_type(2)));
typedef _Float16 h8 __attribute__((ext_vector_type(8)));
typedef unsigned u32x4 __attribute__((ext_vector_type(4)));

__device__ __forceinline__ float fdot2f(h2 a, h2 b, float c) {
#if __has_builtin(__builtin_amdgcn_fdot2)
    return __builtin_amdgcn_fdot2(a, b, c, false);
#else
    return c + (float)a[0] * (float)b[0] + (float)a[1] * (float)b[1];
#endif
}

// tanh via 2^x: tanh(|s|) = (1-e)/(1+e), e = exp(-2|s|) = exp2(-2*log2e*|s|)
__device__ __forceinline__ float fast_tanhf(float s) {
    float av = __builtin_fabsf(s);
    float e  = __builtin_amdgcn_exp2f(-2.8853900817779268f * av);
    float r  = (1.0f - e) * __builtin_amdgcn_rcpf(1.0f + e);
    return __builtin_copysignf(r, s);
}

__global__ void __launch_bounds__(BT, 1) esn_kernel(
    const float* __restrict__ Wh,    // [R, R] row-major fp32
    const float* __restrict__ Win,   // [R, 3]
    const float* __restrict__ x,     // [T, 3]
    float* __restrict__ out,         // [T, 4099]
    unsigned short* __restrict__ pay0,  // packed fp16 payload, even-step reads
    unsigned short* __restrict__ pay1,  // odd-step reads
    unsigned char* __restrict__ flg0,   // per-wave byte flags, even-step reads
    unsigned char* __restrict__ flg1)   // odd-step reads
{
    __shared__ alignas(16) unsigned short hl[R_SIZE];      // 8 KB fp16 bits
    __shared__ float xs[T_STEPS * I_SIZE];                 // 48 KB

    const int tid  = threadIdx.x;
    const int bid  = blockIdx.x;
    const int wv   = tid >> 6;
    const int lane = tid & 63;
    const int r0   = bid * RPB;

    // ---- one-time: this wave's 4 Wh rows -> fp16 registers (128 VGPRs) ----
    h8 wreg[RPW * 8];
    #pragma unroll
    for (int rr = 0; rr < RPW; ++rr) {
        const float* src = Wh + (size_t)(r0 + wv * RPW + rr) * R_SIZE;
        #pragma unroll
        for (int j = 0; j < 8; ++j) {
            int e = (j * 64 + lane) * 8;
            float4 a = *(const float4*)(src + e);
            float4 b = *(const float4*)(src + e + 4);
            h8 hv;
            hv[0] = (_Float16)a.x; hv[1] = (_Float16)a.y;
            hv[2] = (_Float16)a.z; hv[3] = (_Float16)a.w;
            hv[4] = (_Float16)b.x; hv[5] = (_Float16)b.y;
            hv[6] = (_Float16)b.z; hv[7] = (_Float16)b.w;
            wreg[rr * 8 + j] = hv;
        }
    }

    // ---- one-time: stage x into LDS ----
    for (int i = tid; i < T_STEPS * I_SIZE; i += BT) xs[i] = x[i];

    // publisher lanes (lane<4) cache their row's Win and fp32 leak state
    float win0 = 0.f, win1 = 0.f, win2 = 0.f;
    if (lane < RPW) {
        int r = r0 + wv * RPW + lane;
        win0 = Win[(size_t)r * I_SIZE + 0];
        win1 = Win[(size_t)r * I_SIZE + 1];
        win2 = Win[(size_t)r * I_SIZE + 2];
    }
    float hown = 0.0f;   // h0 = 0

    __syncthreads();     // xs visible

    for (int t = 0; t < T_STEPS; ++t) {
        const int par = t & 1;
        const unsigned short* payr = par ? pay1 : pay0;
        unsigned short*       payw = par ? pay0 : pay1;
        const unsigned char*  flr  = par ? flg1 : flg0;
        unsigned char*        flw  = par ? flg0 : flg1;

        // ---- wave 0 polls the 1 KB flag array (8 lines/round) ----
        if (wv == 0) {
            const unsigned splat = (unsigned)(t & 0xff) * 0x01010101u;
            const unsigned* fp = (const unsigned*)flr + lane * 4; // 16 B/lane
            for (;;) {
                u32x4 f;
                asm volatile(
                    "global_load_dwordx4 %0, %1, off sc0 sc1\n\t"
                    "s_waitcnt vmcnt(0)"
                    : "=&v"(f) : "v"(fp) : "memory");
                int ok = (f[0] == splat) & (f[1] == splat) &
                         (f[2] == splat) & (f[3] == splat);
                if (__all(ok)) break;
                __builtin_amdgcn_s_sleep(1);
            }
        }
        __syncthreads();   // #1: flags seen -> whole block may read payload

        // ---- payload: read once, 32 B per thread, split halves ----
        u32x4 p0, p1;
        {
            const char* base = (const char*)payr;
            const u32x4* s0 = (const u32x4*)(base + (size_t)tid * 16);
            const u32x4* s1 = (const u32x4*)(base + 4096 + (size_t)tid * 16);
            asm volatile(
                "global_load_dwordx4 %0, %2, off sc0 sc1\n\t"
                "global_load_dwordx4 %1, %3, off sc0 sc1\n\t"
                "s_waitcnt vmcnt(0)"
                : "=&v"(p0), "=&v"(p1) : "v"(s0), "v"(s1) : "memory");
        }
        *(u32x4*)((char*)hl + (size_t)tid * 16)        = p0;  // stride-16B:
        *(u32x4*)((char*)hl + 4096 + (size_t)tid * 16) = p1;  // conflict-free
        __syncthreads();   // #2: LDS h ready

        // ---- per-lane h chunk into registers (same layout as round 3) ----
        h8 hreg[8];
        const h8* hl8 = (const h8*)hl;
        #pragma unroll
        for (int j = 0; j < 8; ++j) hreg[j] = hl8[j * 64 + lane];

        // ---- 4 rows per wave: register weights, dot2-accumulate ----
        float acc[RPW];
        #pragma unroll
        for (int rr = 0; rr < RPW; ++rr) {
            float a = 0.0f;
            #pragma unroll
            for (int j = 0; j < 8; ++j) {
                h8 w8 = wreg[rr * 8 + j];
                h8 hh = hreg[j];
                a = fdot2f(__builtin_shufflevector(w8, w8, 0, 1),
                           __builtin_shufflevector(hh, hh, 0, 1), a);
                a = fdot2f(__builtin_shufflevector(w8, w8, 2, 3),
                           __builtin_shufflevector(hh, hh, 2, 3), a);
                a = fdot2f(__builtin_shufflevector(w8, w8, 4, 5),
                           __builtin_shufflevector(hh, hh, 4, 5), a);
                a = fdot2f(__builtin_shufflevector(w8, w8, 6, 7),
                           __builtin_shufflevector(hh, hh, 6, 7), a);
            }
            #pragma unroll
            for (int s = 32; s; s >>= 1) a += __shfl_xor(a, s, 64);
            acc[rr] = a;
        }

        // ---- epilogue: lanes 0..3 finish + publish one row each ----
        float hv = 0.0f;
        const int r = r0 + wv * RPW + lane;
        if (lane < RPW) {
            float a = (lane == 0) ? acc[0]
                    : (lane == 1) ? acc[1]
                    : (lane == 2) ? acc[2] : acc[3];
            float u  = xs[t * 3 + 0] * win0 + xs[t * 3 + 1] * win1 +
                       xs[t * 3 + 2] * win2;
            float hn = fast_tanhf(u + a);
            hv = LEAK * hown + (1.0f - LEAK) * hn;
            hown = hv;
            unsigned short hb = __builtin_bit_cast(unsigned short, (_Float16)hv);
            // write-through to coherence point; lands packed-fp16 in place
            asm volatile("global_store_short %0, %1, off sc0 sc1"
                         :: "v"(payw + r), "v"((unsigned)hb) : "memory");
        }
        // release fence: payload stores globally visible before the flag
        asm volatile("s_waitcnt vmcnt(0)" ::: "memory");
        if (lane == 0) {
            unsigned tb = (unsigned)((t + 1) & 0xff);
            asm volatile("global_store_byte %0, %1, off sc0 sc1"
                         :: "v"(flw + bid * NWAVES + wv), "v"(tb) : "memory");
        }
        // out[] store off the critical path (fire-and-forget; its ack is
        // absorbed by the next step's poll waitcnt)
        if (lane < RPW) out[(size_t)t * OUT_COLS + r] = hv;
    }
}

__global__ void copy_x_kernel(const float* __restrict__ x, float* __restrict__ out) {
    int i = blockIdx.x * blockDim.x + threadIdx.x;
    if (i < T_STEPS * I_SIZE) {
        int t = i / I_SIZE, c = i % I_SIZE;
        out[(size_t)t * OUT_COLS + R_SIZE + c] = x[i];
    }
}

extern "C" void kernel_launch(void* const* d_in, const int* in_sizes, int n_in,
                              void* d_out, int out_size, void* d_ws, size_t ws_size,
                              hipStream_t stream) {
    // setup_inputs order: x [T,3], Win [R,3], Wh [R,R]; all fp32.
    const float* x   = (const float*)d_in[0];
    const float* Win = (const float*)d_in[1];
    const float* Wh  = (const float*)d_in[2];
    float* out = (float*)d_out;

    // ws layout: pay0 (8 KB) | pay1 (8 KB) | flg0 (1 KB) | flg1 (1 KB)
    unsigned short* pay0 = (unsigned short*)d_ws;
    unsigned short* pay1 = pay0 + R_SIZE;
    unsigned char*  flg0 = (unsigned char*)(pay1 + R_SIZE);
    unsigned char*  flg1 = flg0 + NFLAGS;

    // zero: pay0=h(0)=0, flg0=tag0 (step-0 readers pass immediately);
    // pay1/flg1 zero != tag 1, so step-1 readers wait.
    hipMemsetAsync(d_ws, 0, 2 * R_SIZE * sizeof(unsigned short) + 2 * NFLAGS,
                   stream);

    copy_x_kernel<<<dim3((T_STEPS * I_SIZE + BT - 1) / BT), dim3(BT), 0, stream>>>(x, out);

    void* args[] = {(void*)&Wh, (void*)&Win, (void*)&x, (void*)&out,
                    (void*)&pay0, (void*)&pay1, (void*)&flg0, (void*)&flg1};
    hipError_t e = hipLaunchCooperativeKernel((void*)esn_kernel, dim3(NB), dim3(BT),
                                              args, 0, stream);
    if (e != hipSuccess) {
        // Fallback: plain launch; 256 blocks x 4 waves always co-resident.
        esn_kernel<<<dim3(NB), dim3(BT), 0, stream>>>(Wh, Win, x, out,
                                                      pay0, pay1, flg0, flg1);
    }
}

// Round 2
// 12108.514 us; speedup vs baseline: 3.1319x; 3.1319x over previous
//
#include <hip/hip_runtime.h>
#include <cmath>

// ESN forward scan on MI355X — round 5.
//
// Round-4 post-mortem (37.9 ms, VALUBusy 3.8%, 2x run variance): the
// flag+fence protocol ADDED two serial fabric round-trips per step
// (store-ack release fence + separate flag->payload load chain) and
// concentrated 1024 byte-stores/step onto 8 cache lines at the coherence
// point (~128 serialized partial-line writes per line per step). Lesson:
// the fused tag|payload dword (one store, one poll load, no fence) is
// latency-optimal per hop — round 3's weakness was only poll VOLUME.
//
// Round 5 = round-3 skeleton + two congestion fixes that add no serial hops:
//   1. 8x replicated exchange: producers store each row's tagged word to 8
//      replicas (independent, self-validating — no fence). Block b polls
//      replica b&7. Per-line reader fan-in per poll round: 256 -> 32.
//   2. Straggler-only re-poll: first round reads all 16 words (mandatory);
//      re-rounds issue the 4x dwordx4 only for lanes with !ok (exec-masked
//      lanes generate no requests) -> steady-state poll traffic ~10x lower.
// Kept from round 4 (orthogonal wins): fast_tanhf (exp2+rcp), x[] staged in
// LDS, out[] store after the publish stores.
//
// Predicted: step 3.96 -> 1.7-2.4 us (dur 7-10 ms), VALUBusy ~20-28%,
// dispatch variance tight. If dur stays ~16 ms the per-line fan-in model is
// wrong -> next round instruments publish->observe latency with s_memtime.

#define T_STEPS  4096
#define R_SIZE   4096
#define I_SIZE   3
#define OUT_COLS (R_SIZE + I_SIZE)   // 4099
#define NB       256                 // blocks == CUs; all co-resident
#define BT       256                 // threads per block (4 waves)
#define RPB      16                  // rows per block
#define RPW      4                   // rows per wave
#define NREP     8                   // exchange replicas (fan-in spreading)
#define LEAK     0.1f

typedef _Float16 h2 __attribute__((ext_vector_type(2)));
typedef _Float16 h4 __attribute__((ext_vector_type(4)));
typedef _Float16 h8 __attribute__((ext_vector_type(8)));
typedef unsigned u32x4 __attribute__((ext_vector_type(4)));

__device__ __forceinline__ float fdot2f(h2 a, h2 b, float c) {
#if __has_builtin(__builtin_amdgcn_fdot2)
    return __builtin_amdgcn_fdot2(a, b, c, false);
#else
    return c + (float)a[0] * (float)b[0] + (float)a[1] * (float)b[1];
#endif
}

// tanh via 2^x: tanh(|s|) = (1-e)/(1+e), e = exp2(-2*log2e*|s|). Error
// ~1e-6, far below the 3.9e-3 fp16 exchange quantization already accepted.
__device__ __forceinline__ float fast_tanhf(float s) {
    float av = __builtin_fabsf(s);
    float e  = __builtin_amdgcn_exp2f(-2.8853900817779268f * av);
    float r  = (1.0f - e) * __builtin_amdgcn_rcpf(1.0f + e);
    return __builtin_copysignf(r, s);
}

// 16 tagged words in flight with L1/L2 bypass, one waitcnt.
__device__ __forceinline__ void poll16(const unsigned* p0, const unsigned* p1,
                                       const unsigned* p2, const unsigned* p3,
                                       u32x4& a0, u32x4& a1, u32x4& a2, u32x4& a3) {
    asm volatile(
        "global_load_dwordx4 %0, %4, off sc0 sc1\n\t"
        "global_load_dwordx4 %1, %5, off sc0 sc1\n\t"
        "global_load_dwordx4 %2, %6, off sc0 sc1\n\t"
        "global_load_dwordx4 %3, %7, off sc0 sc1\n\t"
        "s_waitcnt vmcnt(0)"
        : "=&v"(a0), "=&v"(a1), "=&v"(a2), "=&v"(a3)
        : "v"(p0), "v"(p1), "v"(p2), "v"(p3)
        : "memory");
}

__device__ __forceinline__ _Float16 lo_half(unsigned w) {
    return __builtin_bit_cast(_Float16, (unsigned short)(w & 0xffffu));
}

__device__ __forceinline__ int check16(const u32x4& a0, const u32x4& a1,
                                       const u32x4& a2, const u32x4& a3,
                                       unsigned tg) {
    unsigned bad = ((a0[0] >> 16) ^ tg) | ((a0[1] >> 16) ^ tg) |
                   ((a0[2] >> 16) ^ tg) | ((a0[3] >> 16) ^ tg) |
                   ((a1[0] >> 16) ^ tg) | ((a1[1] >> 16) ^ tg) |
                   ((a1[2] >> 16) ^ tg) | ((a1[3] >> 16) ^ tg) |
                   ((a2[0] >> 16) ^ tg) | ((a2[1] >> 16) ^ tg) |
                   ((a2[2] >> 16) ^ tg) | ((a2[3] >> 16) ^ tg) |
                   ((a3[0] >> 16) ^ tg) | ((a3[1] >> 16) ^ tg) |
                   ((a3[2] >> 16) ^ tg) | ((a3[3] >> 16) ^ tg);
    return bad == 0u;
}

__global__ void __launch_bounds__(BT, 1) esn_kernel(
    const float* __restrict__ Wh,    // [R, R] row-major fp32
    const float* __restrict__ Win,   // [R, 3]
    const float* __restrict__ x,     // [T, 3]
    float* __restrict__ out,         // [T, 4099]
    unsigned* __restrict__ ex0,      // even-step reads: NREP x R dwords
    unsigned* __restrict__ ex1,      // odd-step reads:  NREP x R dwords
    unsigned rep_mask)               // NREP-1, or 0 if ws too small
{
    __shared__ alignas(16) unsigned short hl[R_SIZE];   // 8 KB fp16 bits
    __shared__ float xs[T_STEPS * I_SIZE];              // 48 KB

    const int tid  = threadIdx.x;
    const int bid  = blockIdx.x;
    const int wv   = tid >> 6;
    const int lane = tid & 63;
    const int r0   = bid * RPB;

    // ---- one-time: this wave's 4 Wh rows -> fp16 registers (128 VGPRs) ----
    h8 wreg[RPW * 8];
    #pragma unroll
    for (int rr = 0; rr < RPW; ++rr) {
        const float* src = Wh + (size_t)(r0 + wv * RPW + rr) * R_SIZE;
        #pragma unroll
        for (int j = 0; j < 8; ++j) {
            int e = (j * 64 + lane) * 8;
            float4 a = *(const float4*)(src + e);
            float4 b = *(const float4*)(src + e + 4);
            h8 hv;
            hv[0] = (_Float16)a.x; hv[1] = (_Float16)a.y;
            hv[2] = (_Float16)a.z; hv[3] = (_Float16)a.w;
            hv[4] = (_Float16)b.x; hv[5] = (_Float16)b.y;
            hv[6] = (_Float16)b.z; hv[7] = (_Float16)b.w;
            wreg[rr * 8 + j] = hv;
        }
    }

    // ---- one-time: stage x into LDS ----
    for (int i = tid; i < T_STEPS * I_SIZE; i += BT) xs[i] = x[i];

    // publisher lanes (lane<4) cache their row's Win and fp32 leak state
    float win0 = 0.f, win1 = 0.f, win2 = 0.f;
    if (lane < RPW) {
        int r = r0 + wv * RPW + lane;
        win0 = Win[(size_t)r * I_SIZE + 0];
        win1 = Win[(size_t)r * I_SIZE + 1];
        win2 = Win[(size_t)r * I_SIZE + 2];
    }
    float hown = 0.0f;   // h0 = 0

    // poll pointers into THIS block's replica: thread tid owns words
    // {m*1024 + tid*4 .. +3}, m = 0..3
    const unsigned rep = (unsigned)bid & rep_mask;
    const unsigned* pa[2][4];
    #pragma unroll
    for (int m = 0; m < 4; ++m) {
        pa[0][m] = ex0 + rep * R_SIZE + m * 1024 + tid * 4;
        pa[1][m] = ex1 + rep * R_SIZE + m * 1024 + tid * 4;
    }

    __syncthreads();     // xs visible

    for (int t = 0; t < T_STEPS; ++t) {
        const int par = t & 1;
        unsigned* __restrict__ exw = par ? ex0 : ex1;   // publish tag t+1

        const float xt0 = xs[t * 3 + 0];
        const float xt1 = xs[t * 3 + 1];
        const float xt2 = xs[t * 3 + 2];

        // ---- poll: first round reads all 16 words; re-rounds only for
        //      lanes still failing (exec-masked -> no traffic from done
        //      lanes). Values are final once tag matches (single write per
        //      word per step), so ok lanes keep their registers. ----
        u32x4 a0, a1, a2, a3;
        const unsigned tg = (unsigned)t;
        poll16(pa[par][0], pa[par][1], pa[par][2], pa[par][3], a0, a1, a2, a3);
        int ok = check16(a0, a1, a2, a3, tg);
        while (!__all(ok)) {
            __builtin_amdgcn_s_sleep(1);
            if (!ok) {
                poll16(pa[par][0], pa[par][1], pa[par][2], pa[par][3],
                       a0, a1, a2, a3);
                ok = check16(a0, a1, a2, a3, tg);
            }
        }

        // ---- unpack to LDS (8 B per thread per chunk) ----
        {
            u32x4 aa[4] = {a0, a1, a2, a3};
            #pragma unroll
            for (int m = 0; m < 4; ++m) {
                h4 hv;
                hv[0] = lo_half(aa[m][0]); hv[1] = lo_half(aa[m][1]);
                hv[2] = lo_half(aa[m][2]); hv[3] = lo_half(aa[m][3]);
                *(h4*)&hl[m * 1024 + tid * 4] = hv;
            }
        }
        __syncthreads();

        // ---- per-lane h chunk into registers ----
        h8 hreg[8];
        const h8* hl8 = (const h8*)hl;
        #pragma unroll
        for (int j = 0; j < 8; ++j) hreg[j] = hl8[j * 64 + lane];

        // ---- 4 rows per wave: register weights, dot2-accumulate ----
        float acc[RPW];
        #pragma unroll
        for (int rr = 0; rr < RPW; ++rr) {
            float a = 0.0f;
            #pragma unroll
            for (int j = 0; j < 8; ++j) {
                h8 w8 = wreg[rr * 8 + j];
                h8 hh = hreg[j];
                a = fdot2f(__builtin_shufflevector(w8, w8, 0, 1),
                           __builtin_shufflevector(hh, hh, 0, 1), a);
                a = fdot2f(__builtin_shufflevector(w8, w8, 2, 3),
                           __builtin_shufflevector(hh, hh, 2, 3), a);
                a = fdot2f(__builtin_shufflevector(w8, w8, 4, 5),
                           __builtin_shufflevector(hh, hh, 4, 5), a);
                a = fdot2f(__builtin_shufflevector(w8, w8, 6, 7),
                           __builtin_shufflevector(hh, hh, 6, 7), a);
            }
            #pragma unroll
            for (int s = 32; s; s >>= 1) a += __shfl_xor(a, s, 64);
            acc[rr] = a;
        }

        // ---- epilogue: lanes 0..3 finish + publish one row each into all
        //      replicas (independent self-validating stores, no fence).
        // Barrier-free overwrite safety (unchanged from round 3): a wave
        // reaches step t+1's hl overwrite only after its poll sees tag t+1
        // from ALL blocks, which requires its own sibling waves to have
        // published step t — and each wave's last hl read (hreg load)
        // precedes its own publish. ----
        if (lane < RPW) {
            float a = (lane == 0) ? acc[0]
                    : (lane == 1) ? acc[1]
                    : (lane == 2) ? acc[2] : acc[3];
            float u  = xt0 * win0 + xt1 * win1 + xt2 * win2;
            float hn = fast_tanhf(u + a);
            float hv = LEAK * hown + (1.0f - LEAK) * hn;
            hown = hv;
            const int r = r0 + wv * RPW + lane;
            _Float16 hf = (_Float16)hv;
            unsigned word = ((unsigned)(t + 1) << 16) |
                            (unsigned)__builtin_bit_cast(unsigned short, hf);
            for (unsigned rr2 = 0; rr2 <= rep_mask; ++rr2) {
                asm volatile("global_store_dword %0, %1, off sc0 sc1"
                             :: "v"(exw + rr2 * R_SIZE + r), "v"(word)
                             : "memory");
            }
            // out[] store after publish — off the critical path; its ack is
            // absorbed by the next step's poll waitcnt.
            out[(size_t)t * OUT_COLS + r] = hv;
        }
    }
}

__global__ void copy_x_kernel(const float* __restrict__ x, float* __restrict__ out) {
    int i = blockIdx.x * blockDim.x + threadIdx.x;
    if (i < T_STEPS * I_SIZE) {
        int t = i / I_SIZE, c = i % I_SIZE;
        out[(size_t)t * OUT_COLS + R_SIZE + c] = x[i];
    }
}

extern "C" void kernel_launch(void* const* d_in, const int* in_sizes, int n_in,
                              void* d_out, int out_size, void* d_ws, size_t ws_size,
                              hipStream_t stream) {
    // setup_inputs order: x [T,3], Win [R,3], Wh [R,R]; all fp32.
    const float* x   = (const float*)d_in[0];
    const float* Win = (const float*)d_in[1];
    const float* Wh  = (const float*)d_in[2];
    float* out = (float*)d_out;

    // ws layout: ex0 (NREP*16 KB) | ex1 (NREP*16 KB). Fall back to 1 replica
    // if the workspace is unexpectedly small.
    size_t need8 = (size_t)2 * NREP * R_SIZE * sizeof(unsigned);   // 256 KB
    unsigned nrep = (ws_size >= need8) ? NREP : 1u;
    unsigned rep_mask = nrep - 1u;
    unsigned* ex0 = (unsigned*)d_ws;
    unsigned* ex1 = ex0 + (size_t)nrep * R_SIZE;

    // zero both: ex0 all-zero == (tag 0, h=0) = ready state for step 0;
    // ex1 all-zero == tag 0 != 1, so step-1 readers wait.
    hipMemsetAsync(d_ws, 0, (size_t)2 * nrep * R_SIZE * sizeof(unsigned),
                   stream);

    copy_x_kernel<<<dim3((T_STEPS * I_SIZE + BT - 1) / BT), dim3(BT), 0, stream>>>(x, out);

    void* args[] = {(void*)&Wh, (void*)&Win, (void*)&x, (void*)&out,
                    (void*)&ex0, (void*)&ex1, (void*)&rep_mask};
    hipError_t e = hipLaunchCooperativeKernel((void*)esn_kernel, dim3(NB), dim3(BT),
                                              args, 0, stream);
    if (e != hipSuccess) {
        // Fallback: plain launch; 256 blocks x 4 waves always co-resident.
        esn_kernel<<<dim3(NB), dim3(BT), 0, stream>>>(Wh, Win, x, out,
                                                      ex0, ex1, rep_mask);
    }
}

// Round 3
// 11805.386 us; speedup vs baseline: 3.2123x; 1.0257x over previous
//
#include <hip/hip_runtime.h>
#include <cmath>

// ESN forward scan on MI355X — round 6.
//
// Round-5 result (12.1 ms, 3.0 us/step, VALUBusy 16.4%): replication +
// straggler-only re-poll recovered ~1 us/step. Remaining ~2.5 us/step wait
// decomposes (model) as: (a) per-wave vmcnt is IN-ORDER — the first poll
// round's s_waitcnt vmcnt(0) must drain the wave's own 9 publish store-acks
// (~300-400 ns write-through round trip) before the poll loads can retire;
// (b) the first poll round is issued when no other block can have published
// yet — a guaranteed miss costing a full round and 4 MB of wasted chip-wide
// poll traffic that congests the fabric the publishes are crossing;
// (c) 32K scattered dword stores/step = 32 partial-line writes per L3 line.
//
// Round-6 changes:
//   1. Single-instruction publish: after the full-wave butterfly reduce ALL
//      lanes hold all 4 row sums. Lanes 0-3 build tagged words; 4 shuffles
//      give lanes 0-7 the packed u32x4 {w0,w1,w2,w3}; ONE
//      global_store_dwordx4 with lanes 0-7 active writes all 8 replicas
//      (lane = replica index). Publish vmcnt footprint 9 -> 1 op; L3 line
//      traffic 16 scattered dwords -> 4 aligned 16-B segments per line.
//   2. Pre-poll s_sleep(6) (~160 ns): inside the guaranteed-miss window —
//      drains store-acks off the poll's vmcnt(0) and removes one wasted
//      4 MB poll round per step.
//   3. Safety __syncthreads after the hreg loads: closes the LDS overwrite
//      hazard that previously relied on temporal slack.
//
// Predicted: step 3.0 -> ~2.4 us (dur 9.5-10.5 ms), FETCH -420 MB,
// VALUBusy ~20%. If >=11.5 ms, congestion/drain model exhausted -> next
// round instruments publish->observe latency with s_memtime.

#define T_STEPS  4096
#define R_SIZE   4096
#define I_SIZE   3
#define OUT_COLS (R_SIZE + I_SIZE)   // 4099
#define NB       256                 // blocks == CUs; all co-resident
#define BT       256                 // threads per block (4 waves)
#define RPB      16                  // rows per block
#define RPW      4                   // rows per wave
#define NREP     8                   // exchange replicas (fan-in spreading)
#define LEAK     0.1f

typedef _Float16 h2 __attribute__((ext_vector_type(2)));
typedef _Float16 h4 __attribute__((ext_vector_type(4)));
typedef _Float16 h8 __attribute__((ext_vector_type(8)));
typedef unsigned u32x4 __attribute__((ext_vector_type(4)));

__device__ __forceinline__ float fdot2f(h2 a, h2 b, float c) {
#if __has_builtin(__builtin_amdgcn_fdot2)
    return __builtin_amdgcn_fdot2(a, b, c, false);
#else
    return c + (float)a[0] * (float)b[0] + (float)a[1] * (float)b[1];
#endif
}

// tanh via 2^x: tanh(|s|) = (1-e)/(1+e), e = exp2(-2*log2e*|s|). Error
// ~1e-6, far below the 3.9e-3 fp16 exchange quantization already accepted.
__device__ __forceinline__ float fast_tanhf(float s) {
    float av = __builtin_fabsf(s);
    float e  = __builtin_amdgcn_exp2f(-2.8853900817779268f * av);
    float r  = (1.0f - e) * __builtin_amdgcn_rcpf(1.0f + e);
    return __builtin_copysignf(r, s);
}

// 16 tagged words in flight with L1/L2 bypass, one waitcnt.
__device__ __forceinline__ void poll16(const unsigned* p0, const unsigned* p1,
                                       const unsigned* p2, const unsigned* p3,
                                       u32x4& a0, u32x4& a1, u32x4& a2, u32x4& a3) {
    asm volatile(
        "global_load_dwordx4 %0, %4, off sc0 sc1\n\t"
        "global_load_dwordx4 %1, %5, off sc0 sc1\n\t"
        "global_load_dwordx4 %2, %6, off sc0 sc1\n\t"
        "global_load_dwordx4 %3, %7, off sc0 sc1\n\t"
        "s_waitcnt vmcnt(0)"
        : "=&v"(a0), "=&v"(a1), "=&v"(a2), "=&v"(a3)
        : "v"(p0), "v"(p1), "v"(p2), "v"(p3)
        : "memory");
}

__device__ __forceinline__ _Float16 lo_half(unsigned w) {
    return __builtin_bit_cast(_Float16, (unsigned short)(w & 0xffffu));
}

__device__ __forceinline__ int check16(const u32x4& a0, const u32x4& a1,
                                       const u32x4& a2, const u32x4& a3,
                                       unsigned tg) {
    unsigned bad = ((a0[0] >> 16) ^ tg) | ((a0[1] >> 16) ^ tg) |
                   ((a0[2] >> 16) ^ tg) | ((a0[3] >> 16) ^ tg) |
                   ((a1[0] >> 16) ^ tg) | ((a1[1] >> 16) ^ tg) |
                   ((a1[2] >> 16) ^ tg) | ((a1[3] >> 16) ^ tg) |
                   ((a2[0] >> 16) ^ tg) | ((a2[1] >> 16) ^ tg) |
                   ((a2[2] >> 16) ^ tg) | ((a2[3] >> 16) ^ tg) |
                   ((a3[0] >> 16) ^ tg) | ((a3[1] >> 16) ^ tg) |
                   ((a3[2] >> 16) ^ tg) | ((a3[3] >> 16) ^ tg);
    return bad == 0u;
}

__global__ void __launch_bounds__(BT, 1) esn_kernel(
    const float* __restrict__ Wh,    // [R, R] row-major fp32
    const float* __restrict__ Win,   // [R, 3]
    const float* __restrict__ x,     // [T, 3]
    float* __restrict__ out,         // [T, 4099]
    unsigned* __restrict__ ex0,      // even-step reads: NREP x R dwords
    unsigned* __restrict__ ex1,      // odd-step reads:  NREP x R dwords
    unsigned rep_mask)               // NREP-1, or 0 if ws too small
{
    __shared__ alignas(16) unsigned short hl[R_SIZE];   // 8 KB fp16 bits
    __shared__ float xs[T_STEPS * I_SIZE];              // 48 KB

    const int tid  = threadIdx.x;
    const int bid  = blockIdx.x;
    const int wv   = tid >> 6;
    const int lane = tid & 63;
    const int r0   = bid * RPB;

    // ---- one-time: this wave's 4 Wh rows -> fp16 registers (128 VGPRs) ----
    h8 wreg[RPW * 8];
    #pragma unroll
    for (int rr = 0; rr < RPW; ++rr) {
        const float* src = Wh + (size_t)(r0 + wv * RPW + rr) * R_SIZE;
        #pragma unroll
        for (int j = 0; j < 8; ++j) {
            int e = (j * 64 + lane) * 8;
            float4 a = *(const float4*)(src + e);
            float4 b = *(const float4*)(src + e + 4);
            h8 hv;
            hv[0] = (_Float16)a.x; hv[1] = (_Float16)a.y;
            hv[2] = (_Float16)a.z; hv[3] = (_Float16)a.w;
            hv[4] = (_Float16)b.x; hv[5] = (_Float16)b.y;
            hv[6] = (_Float16)b.z; hv[7] = (_Float16)b.w;
            wreg[rr * 8 + j] = hv;
        }
    }

    // ---- one-time: stage x into LDS ----
    for (int i = tid; i < T_STEPS * I_SIZE; i += BT) xs[i] = x[i];

    // publisher lanes (lane<4) cache their row's Win and fp32 leak state
    float win0 = 0.f, win1 = 0.f, win2 = 0.f;
    if (lane < RPW) {
        int r = r0 + wv * RPW + lane;
        win0 = Win[(size_t)r * I_SIZE + 0];
        win1 = Win[(size_t)r * I_SIZE + 1];
        win2 = Win[(size_t)r * I_SIZE + 2];
    }
    float hown = 0.0f;   // h0 = 0

    // poll pointers into THIS block's replica: thread tid owns words
    // {m*1024 + tid*4 .. +3}, m = 0..3
    const unsigned rep  = (unsigned)bid & rep_mask;
    const unsigned nrep = rep_mask + 1u;
    const unsigned* pa[2][4];
    #pragma unroll
    for (int m = 0; m < 4; ++m) {
        pa[0][m] = ex0 + rep * R_SIZE + m * 1024 + tid * 4;
        pa[1][m] = ex1 + rep * R_SIZE + m * 1024 + tid * 4;
    }

    __syncthreads();     // xs visible

    for (int t = 0; t < T_STEPS; ++t) {
        const int par = t & 1;
        unsigned* __restrict__ exw = par ? ex0 : ex1;   // publish tag t+1

        const float xt0 = xs[t * 3 + 0];
        const float xt1 = xs[t * 3 + 1];
        const float xt2 = xs[t * 3 + 2];

        // ---- pre-poll sleep: we just published; no other block can have
        //      published yet. ~160 ns drains our store-acks off vmcnt and
        //      skips one guaranteed-miss poll round (4 MB chip-wide). ----
        __builtin_amdgcn_s_sleep(6);

        // ---- poll: first round reads all 16 words; re-rounds only for
        //      lanes still failing (exec-masked -> no traffic from done
        //      lanes). ----
        u32x4 a0, a1, a2, a3;
        const unsigned tg = (unsigned)t;
        poll16(pa[par][0], pa[par][1], pa[par][2], pa[par][3], a0, a1, a2, a3);
        int ok = check16(a0, a1, a2, a3, tg);
        while (!__all(ok)) {
            __builtin_amdgcn_s_sleep(1);
            if (!ok) {
                poll16(pa[par][0], pa[par][1], pa[par][2], pa[par][3],
                       a0, a1, a2, a3);
                ok = check16(a0, a1, a2, a3, tg);
            }
        }

        // ---- unpack to LDS (8 B per thread per chunk) ----
        {
            u32x4 aa[4] = {a0, a1, a2, a3};
            #pragma unroll
            for (int m = 0; m < 4; ++m) {
                h4 hv;
                hv[0] = lo_half(aa[m][0]); hv[1] = lo_half(aa[m][1]);
                hv[2] = lo_half(aa[m][2]); hv[3] = lo_half(aa[m][3]);
                *(h4*)&hl[m * 1024 + tid * 4] = hv;
            }
        }
        __syncthreads();   // hl ready for all waves

        // ---- per-lane h chunk into registers ----
        h8 hreg[8];
        const h8* hl8 = (const h8*)hl;
        #pragma unroll
        for (int j = 0; j < 8; ++j) hreg[j] = hl8[j * 64 + lane];
        __syncthreads();   // safety: nobody re-writes hl while others read

        // ---- 4 rows per wave: register weights, dot2-accumulate ----
        float acc[RPW];
        #pragma unroll
        for (int rr = 0; rr < RPW; ++rr) {
            float a = 0.0f;
            #pragma unroll
            for (int j = 0; j < 8; ++j) {
                h8 w8 = wreg[rr * 8 + j];
                h8 hh = hreg[j];
                a = fdot2f(__builtin_shufflevector(w8, w8, 0, 1),
                           __builtin_shufflevector(hh, hh, 0, 1), a);
                a = fdot2f(__builtin_shufflevector(w8, w8, 2, 3),
                           __builtin_shufflevector(hh, hh, 2, 3), a);
                a = fdot2f(__builtin_shufflevector(w8, w8, 4, 5),
                           __builtin_shufflevector(hh, hh, 4, 5), a);
                a = fdot2f(__builtin_shufflevector(w8, w8, 6, 7),
                           __builtin_shufflevector(hh, hh, 6, 7), a);
            }
            #pragma unroll
            for (int s = 32; s; s >>= 1) a += __shfl_xor(a, s, 64);
            acc[rr] = a;
        }

        // ---- epilogue: lanes 0-3 finish their row; lanes 0-7 then publish
        //      all 8 replicas with ONE packed dwordx4 store (lane=replica).
        float hv = 0.0f;
        unsigned word = 0;
        if (lane < RPW) {
            float a = (lane == 0) ? acc[0]
                    : (lane == 1) ? acc[1]
                    : (lane == 2) ? acc[2] : acc[3];
            float u  = xt0 * win0 + xt1 * win1 + xt2 * win2;
            float hn = fast_tanhf(u + a);
            hv = LEAK * hown + (1.0f - LEAK) * hn;
            hown = hv;
            word = ((unsigned)(t + 1) << 16) |
                   (unsigned)__builtin_bit_cast(unsigned short, (_Float16)hv);
        }
        // gather the wave's 4 tagged words into every lane
        unsigned w0 = __shfl(word, 0, 64);
        unsigned w1 = __shfl(word, 1, 64);
        unsigned w2 = __shfl(word, 2, 64);
        unsigned w3 = __shfl(word, 3, 64);
        if ((unsigned)lane < nrep) {
            u32x4 pw = {w0, w1, w2, w3};
            unsigned* dst = exw + (unsigned)lane * R_SIZE + r0 + wv * RPW;
            asm volatile("global_store_dwordx4 %0, %1, off sc0 sc1"
                         :: "v"(dst), "v"(pw) : "memory");
        }
        // out[] store after publish — off the critical path
        if (lane < RPW) {
            out[(size_t)t * OUT_COLS + (r0 + wv * RPW + lane)] = hv;
        }
    }
}

__global__ void copy_x_kernel(const float* __restrict__ x, float* __restrict__ out) {
    int i = blockIdx.x * blockDim.x + threadIdx.x;
    if (i < T_STEPS * I_SIZE) {
        int t = i / I_SIZE, c = i % I_SIZE;
        out[(size_t)t * OUT_COLS + R_SIZE + c] = x[i];
    }
}

extern "C" void kernel_launch(void* const* d_in, const int* in_sizes, int n_in,
                              void* d_out, int out_size, void* d_ws, size_t ws_size,
                              hipStream_t stream) {
    // setup_inputs order: x [T,3], Win [R,3], Wh [R,R]; all fp32.
    const float* x   = (const float*)d_in[0];
    const float* Win = (const float*)d_in[1];
    const float* Wh  = (const float*)d_in[2];
    float* out = (float*)d_out;

    // ws layout: ex0 (NREP*16 KB) | ex1 (NREP*16 KB). Fall back to 1 replica
    // if the workspace is unexpectedly small.
    size_t need8 = (size_t)2 * NREP * R_SIZE * sizeof(unsigned);   // 256 KB
    unsigned nrep = (ws_size >= need8) ? NREP : 1u;
    unsigned rep_mask = nrep - 1u;
    unsigned* ex0 = (unsigned*)d_ws;
    unsigned* ex1 = ex0 + (size_t)nrep * R_SIZE;

    // zero both: ex0 all-zero == (tag 0, h=0) = ready state for step 0;
    // ex1 all-zero == tag 0 != 1, so step-1 readers wait.
    hipMemsetAsync(d_ws, 0, (size_t)2 * nrep * R_SIZE * sizeof(unsigned),
                   stream);

    copy_x_kernel<<<dim3((T_STEPS * I_SIZE + BT - 1) / BT), dim3(BT), 0, stream>>>(x, out);

    void* args[] = {(void*)&Wh, (void*)&Win, (void*)&x, (void*)&out,
                    (void*)&ex0, (void*)&ex1, (void*)&rep_mask};
    hipError_t e = hipLaunchCooperativeKernel((void*)esn_kernel, dim3(NB), dim3(BT),
                                              args, 0, stream);
    if (e != hipSuccess) {
        // Fallback: plain launch; 256 blocks x 4 waves always co-resident.
        esn_kernel<<<dim3(NB), dim3(BT), 0, stream>>>(Wh, Win, x, out,
                                                      ex0, ex1, rep_mask);
    }
}

// Round 5
// 8869.582 us; speedup vs baseline: 4.2756x; 1.3310x over previous
//
#include <hip/hip_runtime.h>
#include <cmath>

// ESN forward scan on MI355X — round 8.
//
// Round-7 bench failed twice with no kernel signal. Its only host-side delta
// vs twice-benched-fine round 6 was hipGetDevice/hipDeviceGetAttribute +
// a function-local static inside kernel_launch (graph-capture tripwire
// candidate). Round 8 = round-6 kernel body, unchanged launch surface,
// plus a SELF-CALIBRATING pacing loop that needs no host queries and no
// clock-rate assumption.
//
// Thesis (from rounds 5-6 data): period 2.88 us/step = local pipeline
// (~0.55) + LLC visibility hop (~0.4) + POLL DESYNC WASTE (~1.3-1.9):
// a poll round costs a full LLC round trip; polls fire unaligned with
// arrivals, so blocks pay guaranteed-miss + re-round quantization every
// step. Traffic-shaving (rounds 5-6) couldn't touch this term.
//
// Round-8 mechanism — per-wave delay-locked loop on ACTUAL arrivals:
//   * Each wave sleeps until tgt = (last poll-success time) + P, then polls.
//   * Feedback per step: first-round MISS -> P += 8 ticks (polled early,
//     paid a re-round); HIT -> P -= 1 tick (shave latency).
//   * Equilibrium (~1/9 miss rate): the single poll fires just after the
//     last arrival -> achieved period converges to pipeline+hop (the true
//     critical path), desync waste collapses.
//   * No division, no cross-block clock agreement, self-healing (tgt in
//     the past => free-run => re-lock), P capped => wait strictly bounded.
//   * P starts at 0 => first steps are byte-for-byte round-6 behavior.
//
// Predicted: dur 11.8 -> 6.5-8.5 ms, FETCH 497 -> ~350 MB, VALUBusy ~25%.
// If >=11 ms WITH a passing bench: desync thesis falsified -> remaining
// wait is genuine visibility latency -> go algorithmic (pipelined
// h-broadcast), stop tuning sync.

#define T_STEPS  4096
#define R_SIZE   4096
#define I_SIZE   3
#define OUT_COLS (R_SIZE + I_SIZE)   // 4099
#define NB       256                 // blocks == CUs; all co-resident
#define BT       256                 // threads per block (4 waves)
#define RPB      16                  // rows per block
#define RPW      4                   // rows per wave
#define NREP     8                   // exchange replicas (fan-in spreading)
#define LEAK     0.1f

typedef _Float16 h2 __attribute__((ext_vector_type(2)));
typedef _Float16 h4 __attribute__((ext_vector_type(4)));
typedef _Float16 h8 __attribute__((ext_vector_type(8)));
typedef unsigned u32x4 __attribute__((ext_vector_type(4)));

__device__ __forceinline__ float fdot2f(h2 a, h2 b, float c) {
#if __has_builtin(__builtin_amdgcn_fdot2)
    return __builtin_amdgcn_fdot2(a, b, c, false);
#else
    return c + (float)a[0] * (float)b[0] + (float)a[1] * (float)b[1];
#endif
}

// tanh via 2^x: tanh(|s|) = (1-e)/(1+e), e = exp2(-2*log2e*|s|). Error
// ~1e-6, far below the 3.9e-3 fp16 exchange quantization already accepted.
__device__ __forceinline__ float fast_tanhf(float s) {
    float av = __builtin_fabsf(s);
    float e  = __builtin_amdgcn_exp2f(-2.8853900817779268f * av);
    float r  = (1.0f - e) * __builtin_amdgcn_rcpf(1.0f + e);
    return __builtin_copysignf(r, s);
}

// 16 tagged words in flight with L1/L2 bypass, one waitcnt.
__device__ __forceinline__ void poll16(const unsigned* p0, const unsigned* p1,
                                       const unsigned* p2, const unsigned* p3,
                                       u32x4& a0, u32x4& a1, u32x4& a2, u32x4& a3) {
    asm volatile(
        "global_load_dwordx4 %0, %4, off sc0 sc1\n\t"
        "global_load_dwordx4 %1, %5, off sc0 sc1\n\t"
        "global_load_dwordx4 %2, %6, off sc0 sc1\n\t"
        "global_load_dwordx4 %3, %7, off sc0 sc1\n\t"
        "s_waitcnt vmcnt(0)"
        : "=&v"(a0), "=&v"(a1), "=&v"(a2), "=&v"(a3)
        : "v"(p0), "v"(p1), "v"(p2), "v"(p3)
        : "memory");
}

__device__ __forceinline__ _Float16 lo_half(unsigned w) {
    return __builtin_bit_cast(_Float16, (unsigned short)(w & 0xffffu));
}

__device__ __forceinline__ int check16(const u32x4& a0, const u32x4& a1,
                                       const u32x4& a2, const u32x4& a3,
                                       unsigned tg) {
    unsigned bad = ((a0[0] >> 16) ^ tg) | ((a0[1] >> 16) ^ tg) |
                   ((a0[2] >> 16) ^ tg) | ((a0[3] >> 16) ^ tg) |
                   ((a1[0] >> 16) ^ tg) | ((a1[1] >> 16) ^ tg) |
                   ((a1[2] >> 16) ^ tg) | ((a1[3] >> 16) ^ tg) |
                   ((a2[0] >> 16) ^ tg) | ((a2[1] >> 16) ^ tg) |
                   ((a2[2] >> 16) ^ tg) | ((a2[3] >> 16) ^ tg) |
                   ((a3[0] >> 16) ^ tg) | ((a3[1] >> 16) ^ tg) |
                   ((a3[2] >> 16) ^ tg) | ((a3[3] >> 16) ^ tg);
    return bad == 0u;
}

__global__ void __launch_bounds__(BT, 1) esn_kernel(
    const float* __restrict__ Wh,    // [R, R] row-major fp32
    const float* __restrict__ Win,   // [R, 3]
    const float* __restrict__ x,     // [T, 3]
    float* __restrict__ out,         // [T, 4099]
    unsigned* __restrict__ ex0,      // even-step reads: NREP x R dwords
    unsigned* __restrict__ ex1,      // odd-step reads:  NREP x R dwords
    unsigned rep_mask)               // NREP-1, or 0 if ws too small
{
    __shared__ alignas(16) unsigned short hl[R_SIZE];   // 8 KB fp16 bits
    __shared__ float xs[T_STEPS * I_SIZE];              // 48 KB

    const int tid  = threadIdx.x;
    const int bid  = blockIdx.x;
    const int wv   = tid >> 6;
    const int lane = tid & 63;
    const int r0   = bid * RPB;

    // ---- one-time: this wave's 4 Wh rows -> fp16 registers (128 VGPRs) ----
    h8 wreg[RPW * 8];
    #pragma unroll
    for (int rr = 0; rr < RPW; ++rr) {
        const float* src = Wh + (size_t)(r0 + wv * RPW + rr) * R_SIZE;
        #pragma unroll
        for (int j = 0; j < 8; ++j) {
            int e = (j * 64 + lane) * 8;
            float4 a = *(const float4*)(src + e);
            float4 b = *(const float4*)(src + e + 4);
            h8 hv;
            hv[0] = (_Float16)a.x; hv[1] = (_Float16)a.y;
            hv[2] = (_Float16)a.z; hv[3] = (_Float16)a.w;
            hv[4] = (_Float16)b.x; hv[5] = (_Float16)b.y;
            hv[6] = (_Float16)b.z; hv[7] = (_Float16)b.w;
            wreg[rr * 8 + j] = hv;
        }
    }

    // ---- one-time: stage x into LDS ----
    for (int i = tid; i < T_STEPS * I_SIZE; i += BT) xs[i] = x[i];

    // publisher lanes (lane<4) cache their row's Win and fp32 leak state
    float win0 = 0.f, win1 = 0.f, win2 = 0.f;
    if (lane < RPW) {
        int r = r0 + wv * RPW + lane;
        win0 = Win[(size_t)r * I_SIZE + 0];
        win1 = Win[(size_t)r * I_SIZE + 1];
        win2 = Win[(size_t)r * I_SIZE + 2];
    }
    float hown = 0.0f;   // h0 = 0

    // poll pointers into THIS block's replica: thread tid owns words
    // {m*1024 + tid*4 .. +3}, m = 0..3
    const unsigned rep  = (unsigned)bid & rep_mask;
    const unsigned nrep = rep_mask + 1u;
    const unsigned* pa[2][4];
    #pragma unroll
    for (int m = 0; m < 4; ++m) {
        pa[0][m] = ex0 + rep * R_SIZE + m * 1024 + tid * 4;
        pa[1][m] = ex1 + rep * R_SIZE + m * 1024 + tid * 4;
    }

    __syncthreads();     // xs visible

    // ---- delay-locked pacing state (per wave, wave-uniform scalars) ----
    unsigned long long tgt = 0;   // next poll time; 0 = no pacing yet
    unsigned P = 0;               // sleep ticks after last poll success

    for (int t = 0; t < T_STEPS; ++t) {
        const int par = t & 1;
        unsigned* __restrict__ exw = par ? ex0 : ex1;   // publish tag t+1

        const float xt0 = xs[t * 3 + 0];
        const float xt1 = xs[t * 3 + 1];
        const float xt2 = xs[t * 3 + 2];

        // ---- drain publish store-acks off vmcnt inside the dead window ----
        __builtin_amdgcn_s_sleep(6);

        // ---- pace: sleep until predicted arrival (bounded; tgt in the
        //      past no-ops -> free-run; P=0 -> round-6 behavior) ----
        if (P) {
            for (int i = 0; i < 4096; ++i) {
                if (__builtin_amdgcn_s_memrealtime() >= tgt) break;
                __builtin_amdgcn_s_sleep(2);
            }
        }

        // ---- poll: first round reads all 16 words; re-rounds only for
        //      lanes still failing (exec-masked -> no traffic). ----
        u32x4 a0, a1, a2, a3;
        const unsigned tg = (unsigned)t;
        poll16(pa[par][0], pa[par][1], pa[par][2], pa[par][3], a0, a1, a2, a3);
        int ok = check16(a0, a1, a2, a3, tg);
        const int missed = !__all(ok);
        if (missed) {
            do {
                __builtin_amdgcn_s_sleep(1);
                if (!ok) {
                    poll16(pa[par][0], pa[par][1], pa[par][2], pa[par][3],
                           a0, a1, a2, a3);
                    ok = check16(a0, a1, a2, a3, tg);
                }
            } while (!__all(ok));
        }

        // ---- DLL update: miss -> polled too early, back off; hit -> shave.
        //      Next poll at (this success time) + P.
        {
            unsigned long long arr = __builtin_amdgcn_s_memrealtime();
            P = missed ? (P + 8u > 2048u ? 2048u : P + 8u)
                       : (P ? P - 1u : 0u);
            tgt = arr + P;
        }

        // ---- unpack to LDS (8 B per thread per chunk) ----
        {
            u32x4 aa[4] = {a0, a1, a2, a3};
            #pragma unroll
            for (int m = 0; m < 4; ++m) {
                h4 hv;
                hv[0] = lo_half(aa[m][0]); hv[1] = lo_half(aa[m][1]);
                hv[2] = lo_half(aa[m][2]); hv[3] = lo_half(aa[m][3]);
                *(h4*)&hl[m * 1024 + tid * 4] = hv;
            }
        }
        __syncthreads();   // hl ready for all waves

        // ---- per-lane h chunk into registers ----
        h8 hreg[8];
        const h8* hl8 = (const h8*)hl;
        #pragma unroll
        for (int j = 0; j < 8; ++j) hreg[j] = hl8[j * 64 + lane];
        __syncthreads();   // safety: nobody re-writes hl while others read

        // ---- 4 rows per wave: register weights, dot2-accumulate ----
        float acc[RPW];
        #pragma unroll
        for (int rr = 0; rr < RPW; ++rr) {
            float a = 0.0f;
            #pragma unroll
            for (int j = 0; j < 8; ++j) {
                h8 w8 = wreg[rr * 8 + j];
                h8 hh = hreg[j];
                a = fdot2f(__builtin_shufflevector(w8, w8, 0, 1),
                           __builtin_shufflevector(hh, hh, 0, 1), a);
                a = fdot2f(__builtin_shufflevector(w8, w8, 2, 3),
                           __builtin_shufflevector(hh, hh, 2, 3), a);
                a = fdot2f(__builtin_shufflevector(w8, w8, 4, 5),
                           __builtin_shufflevector(hh, hh, 4, 5), a);
                a = fdot2f(__builtin_shufflevector(w8, w8, 6, 7),
                           __builtin_shufflevector(hh, hh, 6, 7), a);
            }
            #pragma unroll
            for (int s = 32; s; s >>= 1) a += __shfl_xor(a, s, 64);
            acc[rr] = a;
        }

        // ---- epilogue: lanes 0-3 finish their row; lanes 0-7 publish all
        //      8 replicas with ONE packed dwordx4 store (lane=replica). ----
        float hv = 0.0f;
        unsigned word = 0;
        if (lane < RPW) {
            float a = (lane == 0) ? acc[0]
                    : (lane == 1) ? acc[1]
                    : (lane == 2) ? acc[2] : acc[3];
            float u  = xt0 * win0 + xt1 * win1 + xt2 * win2;
            float hn = fast_tanhf(u + a);
            hv = LEAK * hown + (1.0f - LEAK) * hn;
            hown = hv;
            word = ((unsigned)(t + 1) << 16) |
                   (unsigned)__builtin_bit_cast(unsigned short, (_Float16)hv);
        }
        unsigned w0 = __shfl(word, 0, 64);
        unsigned w1 = __shfl(word, 1, 64);
        unsigned w2 = __shfl(word, 2, 64);
        unsigned w3 = __shfl(word, 3, 64);
        if ((unsigned)lane < nrep) {
            u32x4 pw = {w0, w1, w2, w3};
            unsigned* dst = exw + (unsigned)lane * R_SIZE + r0 + wv * RPW;
            asm volatile("global_store_dwordx4 %0, %1, off sc0 sc1"
                         :: "v"(dst), "v"(pw) : "memory");
        }
        // out[] store after publish — off the critical path
        if (lane < RPW) {
            out[(size_t)t * OUT_COLS + (r0 + wv * RPW + lane)] = hv;
        }
    }
}

__global__ void copy_x_kernel(const float* __restrict__ x, float* __restrict__ out) {
    int i = blockIdx.x * blockDim.x + threadIdx.x;
    if (i < T_STEPS * I_SIZE) {
        int t = i / I_SIZE, c = i % I_SIZE;
        out[(size_t)t * OUT_COLS + R_SIZE + c] = x[i];
    }
}

extern "C" void kernel_launch(void* const* d_in, const int* in_sizes, int n_in,
                              void* d_out, int out_size, void* d_ws, size_t ws_size,
                              hipStream_t stream) {
    // setup_inputs order: x [T,3], Win [R,3], Wh [R,R]; all fp32.
    const float* x   = (const float*)d_in[0];
    const float* Win = (const float*)d_in[1];
    const float* Wh  = (const float*)d_in[2];
    float* out = (float*)d_out;

    // ws layout: ex0 (NREP*16 KB) | ex1 (NREP*16 KB). Fall back to 1 replica
    // if the workspace is unexpectedly small.
    size_t need8 = (size_t)2 * NREP * R_SIZE * sizeof(unsigned);   // 256 KB
    unsigned nrep = (ws_size >= need8) ? NREP : 1u;
    unsigned rep_mask = nrep - 1u;
    unsigned* ex0 = (unsigned*)d_ws;
    unsigned* ex1 = ex0 + (size_t)nrep * R_SIZE;

    // zero both: ex0 all-zero == (tag 0, h=0) = ready state for step 0;
    // ex1 all-zero == tag 0 != 1, so step-1 readers wait.
    hipMemsetAsync(d_ws, 0, (size_t)2 * nrep * R_SIZE * sizeof(unsigned),
                   stream);

    copy_x_kernel<<<dim3((T_STEPS * I_SIZE + BT - 1) / BT), dim3(BT), 0, stream>>>(x, out);

    void* args[] = {(void*)&Wh, (void*)&Win, (void*)&x, (void*)&out,
                    (void*)&ex0, (void*)&ex1, (void*)&rep_mask};
    hipError_t e = hipLaunchCooperativeKernel((void*)esn_kernel, dim3(NB), dim3(BT),
                                              args, 0, stream);
    if (e != hipSuccess) {
        // Fallback: plain launch; 256 blocks x 4 waves always co-resident.
        esn_kernel<<<dim3(NB), dim3(BT), 0, stream>>>(Wh, Win, x, out,
                                                      ex0, ex1, rep_mask);
    }
}

// Round 6
// 8703.176 us; speedup vs baseline: 4.3573x; 1.0191x over previous
//
#include <hip/hip_runtime.h>
#include <cmath>

// ESN forward scan on MI355X — round 9.
//
// Round-8 result: 8.87 ms (2.16 us/step), VALUBusy 20.3%, FETCH 314 MB.
// DLL pacing confirmed the desync thesis (-0.72 us/step). Remaining period
// decomposes into ~0.3-us pieces (model): poll-sweep serialization (the DLL
// ALIGNED all blocks, so the 4 MB sweep hits LLC in one instant ~13 TB/s ->
// serializes ~0.3 us), store visibility ~0.3, load return ~0.25, compute
// ~0.5, DLL margin ~0.35. No dominant term; bundle the clear mechanisms:
//   1. 16 replicas (was 8): same sweep bytes spread over 2x lines/slices ->
//      per-line fan-in 32->16, sweep tail shrinks. (Round 5 proved this
//      axis; cheapest structural lever left.)
//   2. Remove 2nd barrier: poll-pass at t+1 proves all sibling waves
//      published t+1, which happens-after their step-t hl reads (data dep
//      through fdot2). Round 6 ran this exact structure and passed.
//   3. DLL hit-decrement 2 (equilibrium p_miss=1/5, margin at 80th pct
//      instead of 89th) + bookkeeping moved post-publish (off crit path).
//   4. Tag check via v_perm-paired hi-halves: 27 VALU ops vs 47.
//   5. Minor: fixed s_sleep dropped (pace subsumes), u=x*Win pre-poll,
//      unpack via explicit v_perm + u32x2 LDS store.
//
// Predicted: dur 7.8-8.4 ms, VALUBusy ~22%, FETCH ~320 MB, WRITE ~1.65 GB.
// If <2% gain: micro-levers exhausted; structure is converged at fabric
// latency and further gains need a different algorithmic decomposition.

#define T_STEPS  4096
#define R_SIZE   4096
#define I_SIZE   3
#define OUT_COLS (R_SIZE + I_SIZE)   // 4099
#define NB       256                 // blocks == CUs; all co-resident
#define BT       256                 // threads per block (4 waves)
#define RPB      16                  // rows per block
#define RPW      4                   // rows per wave
#define NREP     16                  // exchange replicas (fan-in spreading)
#define LEAK     0.1f

typedef _Float16 h2 __attribute__((ext_vector_type(2)));
typedef _Float16 h8 __attribute__((ext_vector_type(8)));
typedef unsigned u32x2 __attribute__((ext_vector_type(2)));
typedef unsigned u32x4 __attribute__((ext_vector_type(4)));

__device__ __forceinline__ float fdot2f(h2 a, h2 b, float c) {
#if __has_builtin(__builtin_amdgcn_fdot2)
    return __builtin_amdgcn_fdot2(a, b, c, false);
#else
    return c + (float)a[0] * (float)b[0] + (float)a[1] * (float)b[1];
#endif
}

// tanh via 2^x: tanh(|s|) = (1-e)/(1+e), e = exp2(-2*log2e*|s|). Error
// ~1e-6, far below the 3.9e-3 fp16 exchange quantization already accepted.
__device__ __forceinline__ float fast_tanhf(float s) {
    float av = __builtin_fabsf(s);
    float e  = __builtin_amdgcn_exp2f(-2.8853900817779268f * av);
    float r  = (1.0f - e) * __builtin_amdgcn_rcpf(1.0f + e);
    return __builtin_copysignf(r, s);
}

// 16 tagged words in flight with L1/L2 bypass, one waitcnt.
__device__ __forceinline__ void poll16(const unsigned* p0, const unsigned* p1,
                                       const unsigned* p2, const unsigned* p3,
                                       u32x4& a0, u32x4& a1, u32x4& a2, u32x4& a3) {
    asm volatile(
        "global_load_dwordx4 %0, %4, off sc0 sc1\n\t"
        "global_load_dwordx4 %1, %5, off sc0 sc1\n\t"
        "global_load_dwordx4 %2, %6, off sc0 sc1\n\t"
        "global_load_dwordx4 %3, %7, off sc0 sc1\n\t"
        "s_waitcnt vmcnt(0)"
        : "=&v"(a0), "=&v"(a1), "=&v"(a2), "=&v"(a3)
        : "v"(p0), "v"(p1), "v"(p2), "v"(p3)
        : "memory");
}

// v_perm-paired tag check: pack two hi-half tags per dword, xor vs splat.
// 0x07060302 selects bytes {src1[2],src1[3],src0[2],src0[3]} = {hi(b),hi(a)}.
__device__ __forceinline__ unsigned tagbad4(const u32x4& a, unsigned tg2) {
    unsigned t01 = __builtin_amdgcn_perm(a[1], a[0], 0x07060302u) ^ tg2;
    unsigned t23 = __builtin_amdgcn_perm(a[3], a[2], 0x07060302u) ^ tg2;
    return t01 | t23;
}
__device__ __forceinline__ int check16(const u32x4& a0, const u32x4& a1,
                                       const u32x4& a2, const u32x4& a3,
                                       unsigned tg2) {
    unsigned bad = tagbad4(a0, tg2) | tagbad4(a1, tg2) |
                   tagbad4(a2, tg2) | tagbad4(a3, tg2);
    return bad == 0u;
}

__global__ void __launch_bounds__(BT, 1) esn_kernel(
    const float* __restrict__ Wh,    // [R, R] row-major fp32
    const float* __restrict__ Win,   // [R, 3]
    const float* __restrict__ x,     // [T, 3]
    float* __restrict__ out,         // [T, 4099]
    unsigned* __restrict__ ex0,      // even-step reads: nrep x R dwords
    unsigned* __restrict__ ex1,      // odd-step reads:  nrep x R dwords
    unsigned rep_mask)               // nrep-1 (16/8/1 by ws_size)
{
    __shared__ alignas(16) unsigned short hl[R_SIZE];   // 8 KB fp16 bits
    __shared__ float xs[T_STEPS * I_SIZE];              // 48 KB

    const int tid  = threadIdx.x;
    const int bid  = blockIdx.x;
    const int wv   = tid >> 6;
    const int lane = tid & 63;
    const int r0   = bid * RPB;

    // ---- one-time: this wave's 4 Wh rows -> fp16 registers (128 VGPRs) ----
    h8 wreg[RPW * 8];
    #pragma unroll
    for (int rr = 0; rr < RPW; ++rr) {
        const float* src = Wh + (size_t)(r0 + wv * RPW + rr) * R_SIZE;
        #pragma unroll
        for (int j = 0; j < 8; ++j) {
            int e = (j * 64 + lane) * 8;
            float4 a = *(const float4*)(src + e);
            float4 b = *(const float4*)(src + e + 4);
            h8 hv;
            hv[0] = (_Float16)a.x; hv[1] = (_Float16)a.y;
            hv[2] = (_Float16)a.z; hv[3] = (_Float16)a.w;
            hv[4] = (_Float16)b.x; hv[5] = (_Float16)b.y;
            hv[6] = (_Float16)b.z; hv[7] = (_Float16)b.w;
            wreg[rr * 8 + j] = hv;
        }
    }

    // ---- one-time: stage x into LDS ----
    for (int i = tid; i < T_STEPS * I_SIZE; i += BT) xs[i] = x[i];

    // publisher lanes (lane<4) cache their row's Win and fp32 leak state
    float win0 = 0.f, win1 = 0.f, win2 = 0.f;
    if (lane < RPW) {
        int r = r0 + wv * RPW + lane;
        win0 = Win[(size_t)r * I_SIZE + 0];
        win1 = Win[(size_t)r * I_SIZE + 1];
        win2 = Win[(size_t)r * I_SIZE + 2];
    }
    float hown = 0.0f;   // h0 = 0

    // poll pointers into THIS block's replica: thread tid owns words
    // {m*1024 + tid*4 .. +3}, m = 0..3
    const unsigned rep  = (unsigned)bid & rep_mask;
    const unsigned nrep = rep_mask + 1u;
    const unsigned* pa[2][4];
    #pragma unroll
    for (int m = 0; m < 4; ++m) {
        pa[0][m] = ex0 + rep * R_SIZE + m * 1024 + tid * 4;
        pa[1][m] = ex1 + rep * R_SIZE + m * 1024 + tid * 4;
    }

    __syncthreads();     // xs visible

    // ---- delay-locked pacing state (per wave, wave-uniform scalars) ----
    unsigned long long tgt = 0;   // next poll time; 0 = no pacing yet
    unsigned P = 0;               // sleep ticks after previous publish

    for (int t = 0; t < T_STEPS; ++t) {
        const int par = t & 1;
        unsigned* __restrict__ exw = par ? ex0 : ex1;   // publish tag t+1

        // ---- u = x*Win: independent of h -> compute before the poll ----
        float u = 0.0f;
        if (lane < RPW)
            u = xs[t * 3 + 0] * win0 + xs[t * 3 + 1] * win1 +
                xs[t * 3 + 2] * win2;

        // ---- pace: sleep until predicted arrival (bounded; tgt in the
        //      past no-ops -> free-run; P=0 -> free-run) ----
        if (P) {
            for (int i = 0; i < 4096; ++i) {
                if (__builtin_amdgcn_s_memrealtime() >= tgt) break;
                __builtin_amdgcn_s_sleep(2);
            }
        }

        // ---- poll: first round reads all 16 words; re-rounds only for
        //      lanes still failing (exec-masked -> no traffic). ----
        u32x4 a0, a1, a2, a3;
        const unsigned tg2 = (unsigned)t * 0x00010001u;   // tag splat
        poll16(pa[par][0], pa[par][1], pa[par][2], pa[par][3], a0, a1, a2, a3);
        int ok = check16(a0, a1, a2, a3, tg2);
        const int missed = !__all(ok);
        if (missed) {
            do {
                __builtin_amdgcn_s_sleep(1);
                if (!ok) {
                    poll16(pa[par][0], pa[par][1], pa[par][2], pa[par][3],
                           a0, a1, a2, a3);
                    ok = check16(a0, a1, a2, a3, tg2);
                }
            } while (!__all(ok));
        }

        // ---- unpack to LDS: v_perm lo-half pairs, one 8-B store per m ----
        {
            u32x4 aa[4] = {a0, a1, a2, a3};
            #pragma unroll
            for (int m = 0; m < 4; ++m) {
                u32x2 w;
                w[0] = __builtin_amdgcn_perm(aa[m][1], aa[m][0], 0x05040100u);
                w[1] = __builtin_amdgcn_perm(aa[m][3], aa[m][2], 0x05040100u);
                *(u32x2*)&hl[m * 1024 + tid * 4] = w;
            }
        }
        __syncthreads();   // hl ready for all waves
        // NOTE: no second barrier. A sibling wave's step-t+1 publish (seen
        // by our next poll) data-depends on its step-t hreg reads, so
        // poll-pass at t+1 proves all siblings finished reading hl.

        // ---- per-lane h chunk into registers ----
        h8 hreg[8];
        const h8* hl8 = (const h8*)hl;
        #pragma unroll
        for (int j = 0; j < 8; ++j) hreg[j] = hl8[j * 64 + lane];

        // ---- 4 rows per wave: register weights, dot2-accumulate ----
        float acc[RPW];
        #pragma unroll
        for (int rr = 0; rr < RPW; ++rr) {
            float a = 0.0f;
            #pragma unroll
            for (int j = 0; j < 8; ++j) {
                h8 w8 = wreg[rr * 8 + j];
                h8 hh = hreg[j];
                a = fdot2f(__builtin_shufflevector(w8, w8, 0, 1),
                           __builtin_shufflevector(hh, hh, 0, 1), a);
                a = fdot2f(__builtin_shufflevector(w8, w8, 2, 3),
                           __builtin_shufflevector(hh, hh, 2, 3), a);
                a = fdot2f(__builtin_shufflevector(w8, w8, 4, 5),
                           __builtin_shufflevector(hh, hh, 4, 5), a);
                a = fdot2f(__builtin_shufflevector(w8, w8, 6, 7),
                           __builtin_shufflevector(hh, hh, 6, 7), a);
            }
            #pragma unroll
            for (int s = 32; s; s >>= 1) a += __shfl_xor(a, s, 64);
            acc[rr] = a;
        }

        // ---- epilogue: lanes 0-3 finish their row; lanes 0..nrep-1 publish
        //      all replicas with ONE packed dwordx4 store (lane=replica). ----
        float hv = 0.0f;
        unsigned word = 0;
        if (lane < RPW) {
            float a = (lane == 0) ? acc[0]
                    : (lane == 1) ? acc[1]
                    : (lane == 2) ? acc[2] : acc[3];
            float hn = fast_tanhf(u + a);
            hv = LEAK * hown + (1.0f - LEAK) * hn;
            hown = hv;
            word = ((unsigned)(t + 1) << 16) |
                   (unsigned)__builtin_bit_cast(unsigned short, (_Float16)hv);
        }
        unsigned w0 = __shfl(word, 0, 64);
        unsigned w1 = __shfl(word, 1, 64);
        unsigned w2 = __shfl(word, 2, 64);
        unsigned w3 = __shfl(word, 3, 64);
        if ((unsigned)lane < nrep) {
            u32x4 pw = {w0, w1, w2, w3};
            unsigned* dst = exw + (unsigned)lane * R_SIZE + r0 + wv * RPW;
            asm volatile("global_store_dwordx4 %0, %1, off sc0 sc1"
                         :: "v"(dst), "v"(pw) : "memory");
        }

        // ---- DLL bookkeeping off the critical path (post-publish).
        //      miss -> polled too early, +8 ticks; hit -> shave 2.
        //      tgt anchored at publish time; offset self-calibrates. ----
        {
            unsigned long long nowp = __builtin_amdgcn_s_memrealtime();
            P = missed ? (P + 8u > 2048u ? 2048u : P + 8u)
                       : (P >= 2u ? P - 2u : 0u);
            tgt = nowp + P;
        }

        // out[] store after publish — off the critical path
        if (lane < RPW) {
            out[(size_t)t * OUT_COLS + (r0 + wv * RPW + lane)] = hv;
        }
    }
}

__global__ void copy_x_kernel(const float* __restrict__ x, float* __restrict__ out) {
    int i = blockIdx.x * blockDim.x + threadIdx.x;
    if (i < T_STEPS * I_SIZE) {
        int t = i / I_SIZE, c = i % I_SIZE;
        out[(size_t)t * OUT_COLS + R_SIZE + c] = x[i];
    }
}

extern "C" void kernel_launch(void* const* d_in, const int* in_sizes, int n_in,
                              void* d_out, int out_size, void* d_ws, size_t ws_size,
                              hipStream_t stream) {
    // setup_inputs order: x [T,3], Win [R,3], Wh [R,R]; all fp32.
    const float* x   = (const float*)d_in[0];
    const float* Win = (const float*)d_in[1];
    const float* Wh  = (const float*)d_in[2];
    float* out = (float*)d_out;

    // ws layout: ex0 (nrep*16 KB) | ex1 (nrep*16 KB). nrep = 16 -> 512 KB;
    // fall back to 8 (256 KB, round-8 config) then 1 if ws is small.
    size_t need16 = (size_t)2 * 16 * R_SIZE * sizeof(unsigned);   // 512 KB
    size_t need8  = (size_t)2 *  8 * R_SIZE * sizeof(unsigned);   // 256 KB
    unsigned nrep = (ws_size >= need16) ? 16u : (ws_size >= need8 ? 8u : 1u);
    unsigned rep_mask = nrep - 1u;
    unsigned* ex0 = (unsigned*)d_ws;
    unsigned* ex1 = ex0 + (size_t)nrep * R_SIZE;

    // zero both: ex0 all-zero == (tag 0, h=0) = ready state for step 0;
    // ex1 all-zero == tag 0 != 1, so step-1 readers wait.
    hipMemsetAsync(d_ws, 0, (size_t)2 * nrep * R_SIZE * sizeof(unsigned),
                   stream);

    copy_x_kernel<<<dim3((T_STEPS * I_SIZE + BT - 1) / BT), dim3(BT), 0, stream>>>(x, out);

    void* args[] = {(void*)&Wh, (void*)&Win, (void*)&x, (void*)&out,
                    (void*)&ex0, (void*)&ex1, (void*)&rep_mask};
    hipError_t e = hipLaunchCooperativeKernel((void*)esn_kernel, dim3(NB), dim3(BT),
                                              args, 0, stream);
    if (e != hipSuccess) {
        // Fallback: plain launch; 256 blocks x 4 waves always co-resident.
        esn_kernel<<<dim3(NB), dim3(BT), 0, stream>>>(Wh, Win, x, out,
                                                      ex0, ex1, rep_mask);
    }
}